// Round 2
// baseline (5975.746 us; speedup 1.0000x reference)
//
#include <hip/hip_runtime.h>

#define B_    256
#define S_    1024
#define H_    512
#define G4_   2048
#define T_    256
#define NBLK  256
#define NTHR  1024
#define BB    16          // batches per batch-group
#define NBG   16          // batch groups
#define LBN   16          // blocks per batch-group
#define HS2   260         // hi/lo plane row stride in words (256 + 4 pad)
#define AUXC  0x11        // CPol sc0|sc1: coherent read at MALL (agent scope)

typedef short bf8v  __attribute__((ext_vector_type(8)));   // 8 bf16 = 4 VGPR
typedef float f4v   __attribute__((ext_vector_type(4)));
typedef int   i32x4 __attribute__((ext_vector_type(4)));

typedef const __attribute__((address_space(1))) void gas_void;
typedef __attribute__((address_space(3))) void       las_void;

#define PERM_HI 0x07060302u   // [src0.hi16 | src1.hi16] (low short = src1.hi16)

// validated agent-scope helpers (compiler codegen, as in the 3706us baseline)
__device__ __forceinline__ unsigned ald(const unsigned* a)
{
    return __hip_atomic_load(a, __ATOMIC_RELAXED, __HIP_MEMORY_SCOPE_AGENT);
}
__device__ __forceinline__ void aadd(unsigned* a)
{
    __hip_atomic_fetch_add(a, 1u, __ATOMIC_RELAXED, __HIP_MEMORY_SCOPE_AGENT);
}
__device__ __forceinline__ void vm0() { asm volatile("s_waitcnt vmcnt(0)" ::: "memory"); }

// ---------------------------------------------------------------------------
// W2[j][k] = dec_Whh[j][k] + dec_Wih[j]*lin_W[k]; dbias[j] = dec biases fused
// ---------------------------------------------------------------------------
__global__ void fuse_dec_weights(const float* __restrict__ dec_Whh,
                                 const float* __restrict__ dec_Wih,
                                 const float* __restrict__ lin_W,
                                 const float* __restrict__ dec_bih,
                                 const float* __restrict__ dec_bhh,
                                 const float* __restrict__ lin_b,
                                 float* __restrict__ W2,
                                 float* __restrict__ dbias)
{
    int idx = blockIdx.x * 256 + threadIdx.x;
    int j = idx >> 9, k = idx & 511;
    W2[idx] = fmaf(dec_Wih[j], lin_W[k], dec_Whh[idx]);
    if (idx < G4_)
        dbias[idx] = dec_bih[idx] + dec_bhh[idx] + dec_Wih[idx] * lin_b[0];
}

// fast sigmoid/tanh: v_exp + v_rcp (rel err ~1e-7; margin 7x at 6e-5)
__device__ __forceinline__ float fsig(float x)
{
    return __builtin_amdgcn_rcpf(1.0f + __expf(-x));
}
__device__ __forceinline__ float ftanh(float x)
{
    return fmaf(-2.0f, __builtin_amdgcn_rcpf(1.0f + __expf(2.0f * x)), 1.0f);
}

// ---------------------------------------------------------------------------
// Persistent kernel, early-signal schedule.
// Per step: [w15 polls bg counter] SY_A -> stage -> SY2 -> dots -> writegb
// -> SY3 -> leaders reduce+lstm+storeh+vmcnt(0)+add.  Leader adds (4/block,
// 64/bg) post right after the h stores drain to MALL — the consumer-side
// invariant (all stage DMA reads of a buffer finish before any block's SY3,
// hence before any add, hence before the buffer is overwritten next step)
// is the same one the validated 2-barrier bg_barrier provided.
// Decoder projection runs BEFORE the wait on the previous step's staged h
// (same values, hidden under the inter-block wait).
// ---------------------------------------------------------------------------
__global__ void __launch_bounds__(NTHR)
seq2seq_kernel(const float* __restrict__ inputs,
               const float* __restrict__ enc_Wih,
               const float* __restrict__ enc_bih,
               const float* __restrict__ enc_bhh,
               const float* __restrict__ dec_Wih,
               const float* __restrict__ lin_W,
               const float* __restrict__ lin_b,
               const float* __restrict__ enc_Whh,
               const float* __restrict__ W2,
               const float* __restrict__ dbias,
               unsigned* __restrict__ hiA, unsigned* __restrict__ loA,
               unsigned* __restrict__ hiB, unsigned* __restrict__ loB,
               float* __restrict__ xcor,
               unsigned* __restrict__ bars,
               float* __restrict__ out)
{
    __shared__ unsigned hs_hi[BB * HS2];     // 16.6 KB: h hi-bf16 plane
    __shared__ unsigned hs_lo[BB * HS2];     // 16.6 KB: h lo-bf16 plane
    __shared__ float gbuf[3 * 4 * 2 * 272];  // 26.1 KB: kset partial f4v slots

    const int tid  = threadIdx.x;
    const int w    = tid >> 6;               // wave 0..15
    const int lane = tid & 63;
    const int quad = lane >> 4;              // 0..3
    const int mn   = lane & 15;              // MFMA m/n index
    const int rs   = w & 3;                  // rowset 0..3
    const int ks   = w >> 2;                 // kset 0..3 (128 k each)
    const int bg   = blockIdx.x & (NBG - 1);
    const int lb   = blockIdx.x >> 4;        // hidden-slice owner 0..15
    const int bgbase = bg * BB;
    const bool leader = (ks == 3);
    const int pidx = lb * 16 + rs * 4 + quad;         // hid-pair index
    const int hid0 = lb * 32 + rs * 8 + 2 * quad;

    unsigned* arr = bars + bg * 64;          // per-bg monotonic signal counter

    // A rows: m = mn -> gate = mn&3, hsel = mn>>2; hsub = rs*8 + 2*hsel + p
    i32x4 Ah[2][4], Al[2][4];                // 64 regs: weight frags hi/lo
    auto loadA = [&](const float* __restrict__ W) {
        #pragma unroll
        for (int p = 0; p < 2; ++p) {
            const int grow = (mn & 3) * H_ + lb * 32 + rs * 8 + 2 * (mn >> 2) + p;
            const float* rowp = W + (size_t)grow * H_ + ks * 128 + quad * 8;
            #pragma unroll
            for (int l = 0; l < 4; ++l) {
                const float* rp = rowp + l * 32;
                float4 f0 = *(const float4*)rp;
                float4 f1 = *(const float4*)(rp + 4);
                unsigned b0 = __float_as_uint(f0.x), b1 = __float_as_uint(f0.y);
                unsigned b2 = __float_as_uint(f0.z), b3 = __float_as_uint(f0.w);
                unsigned b4 = __float_as_uint(f1.x), b5 = __float_as_uint(f1.y);
                unsigned b6 = __float_as_uint(f1.z), b7 = __float_as_uint(f1.w);
                i32x4 hi, lo;
                hi.x = __builtin_amdgcn_perm(b1, b0, PERM_HI);
                hi.y = __builtin_amdgcn_perm(b3, b2, PERM_HI);
                hi.z = __builtin_amdgcn_perm(b5, b4, PERM_HI);
                hi.w = __builtin_amdgcn_perm(b7, b6, PERM_HI);
                float r0 = f0.x - __uint_as_float(b0 & 0xffff0000u);
                float r1 = f0.y - __uint_as_float(b1 & 0xffff0000u);
                float r2 = f0.z - __uint_as_float(b2 & 0xffff0000u);
                float r3 = f0.w - __uint_as_float(b3 & 0xffff0000u);
                float r4 = f1.x - __uint_as_float(b4 & 0xffff0000u);
                float r5 = f1.y - __uint_as_float(b5 & 0xffff0000u);
                float r6 = f1.z - __uint_as_float(b6 & 0xffff0000u);
                float r7 = f1.w - __uint_as_float(b7 & 0xffff0000u);
                lo.x = __builtin_amdgcn_perm(__float_as_uint(r1), __float_as_uint(r0), PERM_HI);
                lo.y = __builtin_amdgcn_perm(__float_as_uint(r3), __float_as_uint(r2), PERM_HI);
                lo.z = __builtin_amdgcn_perm(__float_as_uint(r5), __float_as_uint(r4), PERM_HI);
                lo.w = __builtin_amdgcn_perm(__float_as_uint(r7), __float_as_uint(r6), PERM_HI);
                Ah[p][l] = hi; Al[p][l] = lo;
            }
        }
    };

    // stage: wave w DMAs batch-row (bgbase+w) of both planes into LDS (async)
    auto stage = [&](const unsigned* hi_src, const unsigned* lo_src) {
        const size_t off = (size_t)(bgbase + w) * 256 + lane * 4;
        __builtin_amdgcn_global_load_lds((gas_void*)(hi_src + off),
                                         (las_void*)(hs_hi + w * HS2), 16, 0, AUXC);
        __builtin_amdgcn_global_load_lds((gas_void*)(lo_src + off),
                                         (las_void*)(hs_lo + w * HS2), 16, 0, AUXC);
    };

    // 3-term split-bf16 MFMA over 2 m-tiles x this wave's 128-k range
    auto dots = [&](f4v& acc0, f4v& acc1) {
        acc0 = f4v{0.f, 0.f, 0.f, 0.f};
        acc1 = f4v{0.f, 0.f, 0.f, 0.f};
        #pragma unroll
        for (int l = 0; l < 4; ++l) {
            const int boff = mn * HS2 + ks * 64 + l * 16 + quad * 4;
            i32x4 bhv = *(const i32x4*)(hs_hi + boff);
            i32x4 blv = *(const i32x4*)(hs_lo + boff);
            bf8v bh = __builtin_bit_cast(bf8v, bhv);
            bf8v bl = __builtin_bit_cast(bf8v, blv);
            bf8v a0h = __builtin_bit_cast(bf8v, Ah[0][l]);
            bf8v a0l = __builtin_bit_cast(bf8v, Al[0][l]);
            bf8v a1h = __builtin_bit_cast(bf8v, Ah[1][l]);
            bf8v a1l = __builtin_bit_cast(bf8v, Al[1][l]);
            acc0 = __builtin_amdgcn_mfma_f32_16x16x32_bf16(a0h, bh, acc0, 0, 0, 0);
            acc1 = __builtin_amdgcn_mfma_f32_16x16x32_bf16(a1h, bh, acc1, 0, 0, 0);
            acc0 = __builtin_amdgcn_mfma_f32_16x16x32_bf16(a0l, bh, acc0, 0, 0, 0);
            acc1 = __builtin_amdgcn_mfma_f32_16x16x32_bf16(a1l, bh, acc1, 0, 0, 0);
            acc0 = __builtin_amdgcn_mfma_f32_16x16x32_bf16(a0h, bl, acc0, 0, 0, 0);
            acc1 = __builtin_amdgcn_mfma_f32_16x16x32_bf16(a1h, bl, acc1, 0, 0, 0);
        }
    };

    auto writegb = [&](f4v a0, f4v a1) {     // ks<3 waves park partials
        float* gp = gbuf + ((ks * 4 + rs) * 2) * 272 + quad * 68 + mn * 4;
        *(f4v*)gp = a0;
        *(f4v*)(gp + 272) = a1;
    };
    auto reduceg = [&](f4v& a0, f4v& a1) {   // leader sums 3 parked + own
        const int gb = (rs * 2) * 272 + quad * 68 + mn * 4;
        a0 += *(const f4v*)(gbuf + gb);
        a0 += *(const f4v*)(gbuf + gb + 2176);
        a0 += *(const f4v*)(gbuf + gb + 4352);
        a1 += *(const f4v*)(gbuf + gb + 272);
        a1 += *(const f4v*)(gbuf + gb + 272 + 2176);
        a1 += *(const f4v*)(gbuf + gb + 272 + 4352);
    };

    // LSTM cell on an accumulator holding (i,f,g,o)
    auto lstm = [&](f4v g, float& cc) -> float {
        float i_ = fsig(g[0]), f_ = fsig(g[1]);
        float g_ = ftanh(g[2]), o_ = fsig(g[3]);
        float cn = fmaf(f_, cc, i_ * g_);
        cc = cn;
        return o_ * ftanh(cn);
    };

    auto storeh = [&](unsigned* hn, unsigned* ln, float h0, float h1) {
        unsigned b0 = __float_as_uint(h0), b1 = __float_as_uint(h1);
        unsigned hiw = __builtin_amdgcn_perm(b1, b0, PERM_HI);
        float r0 = h0 - __uint_as_float(b0 & 0xffff0000u);
        float r1 = h1 - __uint_as_float(b1 & 0xffff0000u);
        unsigned low = __builtin_amdgcn_perm(__float_as_uint(r1),
                                             __float_as_uint(r0), PERM_HI);
        size_t pa = (size_t)(bgbase + mn) * 256 + pidx;
        __hip_atomic_store(hn + pa, hiw, __ATOMIC_RELAXED, __HIP_MEMORY_SCOPE_AGENT);
        __hip_atomic_store(ln + pa, low, __ATOMIC_RELAXED, __HIP_MEMORY_SCOPE_AGENT);
    };

    // h[row b]·lin_W from the staged hi/lo planes; result on lane 0
    auto projrow = [&](int b) -> float {
        const unsigned* hh = hs_hi + b * HS2 + 4 * lane;
        const unsigned* hl = hs_lo + b * HS2 + 4 * lane;
        uint4 uh = *(const uint4*)hh;
        uint4 ul = *(const uint4*)hl;
        const float4* lwp = (const float4*)(lin_W + 8 * lane);
        float4 v0 = lwp[0], v1 = lwp[1];
        #define RL(h, l) (__uint_as_float((h) << 16) + __uint_as_float((l) << 16))
        #define RH(h, l) (__uint_as_float((h) & 0xffff0000u) + __uint_as_float((l) & 0xffff0000u))
        float s = RL(uh.x, ul.x) * v0.x + RH(uh.x, ul.x) * v0.y;
        s = fmaf(RL(uh.y, ul.y), v0.z, s); s = fmaf(RH(uh.y, ul.y), v0.w, s);
        s = fmaf(RL(uh.z, ul.z), v1.x, s); s = fmaf(RH(uh.z, ul.z), v1.y, s);
        s = fmaf(RL(uh.w, ul.w), v1.z, s); s = fmaf(RH(uh.w, ul.w), v1.w, s);
        #undef RL
        #undef RH
        s += __shfl_down(s, 32); s += __shfl_down(s, 16); s += __shfl_down(s, 8);
        s += __shfl_down(s, 4);  s += __shfl_down(s, 2);  s += __shfl_down(s, 1);
        return s;
    };

    // w15 (a leader) polls the bg counter; everyone else waits at SY_A.
    auto wait_ph = [&](int phv) {
        const unsigned tgt = 64u * (unsigned)(phv + 1);
        while (ald(arr) < tgt) { }
    };

    const float linb = lin_b[0];

    // encoder per-cell constants (leaders only; 16 regs)
    float encW[2][4], encB[2][4];
    if (leader) {
        #pragma unroll
        for (int p = 0; p < 2; ++p)
            #pragma unroll
            for (int g4 = 0; g4 < 4; ++g4) {
                const int j = g4 * H_ + hid0 + p;
                encW[p][g4] = enc_Wih[j];
                encB[p][g4] = enc_bih[j] + enc_bhh[j];
            }
    }

    loadA(enc_Whh);

    // h_0 = 0 (leaders cover all 512 cells per block), drain, then signal
    if (leader) {
        size_t pa = (size_t)(bgbase + mn) * 256 + pidx;
        __hip_atomic_store(hiA + pa, 0u, __ATOMIC_RELAXED, __HIP_MEMORY_SCOPE_AGENT);
        __hip_atomic_store(loA + pa, 0u, __ATOMIC_RELAXED, __HIP_MEMORY_SCOPE_AGENT);
        vm0();
        if (lane == 0) aadd(arr);
    }

    float cc0 = 0.f, cc1 = 0.f;
    unsigned *hic = hiA, *loc = loA, *hin = hiB, *lon = loB;
    int ph = 0;

    // ---------------- encoder: 1024 steps ----------------
    #pragma unroll 1
    for (int t = 0; t < S_; ++t) {
        float xv = leader ? inputs[(size_t)(bgbase + mn) * S_ + t] : 0.f;
        if (w == 15) wait_ph(ph);
        ++ph;
        __syncthreads();                  // SY_A: release on signal
        stage(hic, loc);
        __syncthreads();                  // SY2: staging complete
        f4v acc0, acc1;
        dots(acc0, acc1);
        if (!leader) writegb(acc0, acc1);
        __syncthreads();                  // SY3: partials parked, hs reads done
        if (leader) {
            reduceg(acc0, acc1);
            #pragma unroll
            for (int g4 = 0; g4 < 4; ++g4) {
                acc0[g4] += fmaf(xv, encW[0][g4], encB[0][g4]);
                acc1[g4] += fmaf(xv, encW[1][g4], encB[1][g4]);
            }
            float h0 = lstm(acc0, cc0);
            float h1 = lstm(acc1, cc1);
            storeh(hin, lon, h0, h1);
            vm0();                         // h at MALL before the signal
            if (lane == 0) aadd(arr);      // early signal
        }
        unsigned* t1 = hic; hic = hin; hin = t1;
        unsigned* t2 = loc; loc = lon; lon = t2;
    }

    // ---------------- xcor phase + decoder weight swap ----------------
    f4v db0{0.f,0.f,0.f,0.f}, db1{0.f,0.f,0.f,0.f};
    float dwa[4] = {0,0,0,0}, dwb[4] = {0,0,0,0};
    if (w == 15) wait_ph(ph);
    ++ph;
    __syncthreads();                      // SY_A
    stage(hic, loc);
    __syncthreads();                      // SY2
    if (w == 0) {                         // xcor[b = bgbase+lb] per block
        float s = projrow(lb);
        if (lane == 0) {
            float x0 = inputs[(size_t)(bgbase + lb) * S_ + (S_ - 1)];
            __hip_atomic_store(&xcor[bgbase + lb], x0 - (s + linb),
                               __ATOMIC_RELAXED, __HIP_MEMORY_SCOPE_AGENT);
        }
    }
    loadA(W2);
    if (leader) {                         // hoisted loop-invariant constants
        #pragma unroll
        for (int g4 = 0; g4 < 4; ++g4) {
            float2 d = *(const float2*)(dbias + g4 * H_ + hid0);
            db0[g4] = d.x; db1[g4] = d.y;
            float2 dw = *(const float2*)(dec_Wih + g4 * H_ + hid0);
            dwa[g4] = dw.x; dwb[g4] = dw.y;
        }
    }
    __syncthreads();                      // SY3: xcor store drained before adds
    if (leader && lane == 0) aadd(arr);

    // ---------------- decoder: 256 steps ----------------
    #pragma unroll 1
    for (int t = 0; t < T_; ++t) {
        // deferred projection: old hs = h staged at step t-1 -> out[t-2].
        // Runs before the wait (hidden); LDS reads drain at SY_A.
        if (w == 0 && t >= 2) {
            float s = projrow(lb);
            if (lane == 0)
                out[(size_t)(bgbase + lb) * T_ + (t - 2)] = s + linb;
        }
        if (w == 15) wait_ph(ph);
        ++ph;
        __syncthreads();                  // SY_A
        stage(hic, loc);
        __syncthreads();                  // SY2
        f4v acc0, acc1;
        dots(acc0, acc1);
        if (!leader) writegb(acc0, acc1);
        __syncthreads();                  // SY3
        if (leader) {
            reduceg(acc0, acc1);
            acc0 += db0;
            acc1 += db1;
            if (t == 0) {                 // true x0 correction through dec_Wih
                float xc = __hip_atomic_load(&xcor[bgbase + mn],
                                             __ATOMIC_RELAXED, __HIP_MEMORY_SCOPE_AGENT);
                #pragma unroll
                for (int g4 = 0; g4 < 4; ++g4) {
                    acc0[g4] = fmaf(xc, dwa[g4], acc0[g4]);
                    acc1[g4] = fmaf(xc, dwb[g4], acc1[g4]);
                }
            }
            float h0 = lstm(acc0, cc0);
            float h1 = lstm(acc1, cc1);
            storeh(hin, lon, h0, h1);
            vm0();
            if (lane == 0) aadd(arr);
        }
        unsigned* t1 = hic; hic = hin; hin = t1;
        unsigned* t2 = loc; loc = lon; lon = t2;
    }

    // ---------------- epilogue: out[:, T-2] and out[:, T-1] ----------------
    if (w == 15) wait_ph(ph);
    __syncthreads();                      // SY_A
    if (w == 0) {                         // old hs = h_{T-1} -> out[T-2]
        float s = projrow(lb);
        if (lane == 0)
            out[(size_t)(bgbase + lb) * T_ + (T_ - 2)] = s + linb;
    }
    __syncthreads();                      // protect old hs until reads drain
    stage(hic, loc);
    __syncthreads();
    if (w == 0) {                         // fresh hs = h_T -> out[T-1]
        float s = projrow(lb);
        if (lane == 0)
            out[(size_t)(bgbase + lb) * T_ + (T_ - 1)] = s + linb;
    }
}

// ---------------------------------------------------------------------------
extern "C" void kernel_launch(void* const* d_in, const int* in_sizes, int n_in,
                              void* d_out, int out_size, void* d_ws, size_t ws_size,
                              hipStream_t stream)
{
    (void)in_sizes; (void)n_in; (void)out_size; (void)ws_size;

    const float* inputs  = (const float*)d_in[0];
    const float* enc_Wih = (const float*)d_in[1];
    const float* enc_Whh = (const float*)d_in[2];
    const float* enc_bih = (const float*)d_in[3];
    const float* enc_bhh = (const float*)d_in[4];
    const float* dec_Wih = (const float*)d_in[5];
    const float* dec_Whh = (const float*)d_in[6];
    const float* dec_bih = (const float*)d_in[7];
    const float* dec_bhh = (const float*)d_in[8];
    const float* lin_W   = (const float*)d_in[9];
    const float* lin_b   = (const float*)d_in[10];
    float* out = (float*)d_out;

    // ws: W2 (4MB) | dbias (8KB) | hiA|loA|hiB|loB (1MB) | xcor | bars
    float* W2      = (float*)d_ws;
    float* dbias   = W2 + (size_t)G4_ * H_;
    unsigned* hiA  = (unsigned*)(dbias + G4_);
    unsigned* loA  = hiA + (size_t)B_ * 256;
    unsigned* loB  = hiA + (size_t)B_ * 256 * 3;
    unsigned* hiB  = hiA + (size_t)B_ * 256 * 2;
    float* xcor    = (float*)(hiA + (size_t)B_ * 256 * 4);
    unsigned* bars = (unsigned*)(xcor + B_);

    hipMemsetAsync((void*)bars, 0, NBG * 64 * sizeof(unsigned), stream);

    hipLaunchKernelGGL(fuse_dec_weights, dim3((G4_ * H_) / 256), dim3(256), 0, stream,
                       dec_Whh, dec_Wih, lin_W, dec_bih, dec_bhh, lin_b, W2, dbias);

    void* args[] = {
        (void*)&inputs, (void*)&enc_Wih, (void*)&enc_bih, (void*)&enc_bhh,
        (void*)&dec_Wih, (void*)&lin_W, (void*)&lin_b,
        (void*)&enc_Whh, (void*)&W2, (void*)&dbias,
        (void*)&hiA, (void*)&loA, (void*)&hiB, (void*)&loB,
        (void*)&xcor, (void*)&bars, (void*)&out
    };
    hipLaunchCooperativeKernel((void*)seq2seq_kernel, dim3(NBLK), dim3(NTHR),
                               args, 0, stream);
}